// Round 13
// baseline (297.623 us; speedup 1.0000x reference)
//
#include <hip/hip_runtime.h>
#include <math.h>

#define EPS 1e-5f
#define KEXP 4.8089834696298780f  // log2(e)/0.3 : exp(x/h) == exp2(x*KEXP)

typedef short short8 __attribute__((ext_vector_type(8)));
typedef float f32x16 __attribute__((ext_vector_type(16)));

static __device__ __forceinline__ unsigned short f2bf(float x) {
  unsigned int b = __float_as_uint(x);
  b += 0x7FFFu + ((b >> 16) & 1u);  // RNE
  return (unsigned short)(b >> 16);
}
static __device__ __forceinline__ unsigned encf(float f) {
  unsigned b = __float_as_uint(f);
  return (b & 0x80000000u) ? ~b : (b | 0x80000000u);
}
static __device__ __forceinline__ float decf(unsigned u) {
  return (u & 0x80000000u) ? __uint_as_float(u & 0x7FFFFFFFu)
                           : __uint_as_float(~u);
}
// nested fmaxf -> clang fuses to v_max3_f32 (T17)
static __device__ __forceinline__ float fmax3(float a, float b, float c) {
  return fmaxf(fmaxf(a, b), c);
}

// async global->LDS, 16B per lane (lane l lands at lds_base + 16*l)
static __device__ __forceinline__ void dma16(const uint4* g, uint4* l) {
  __builtin_amdgcn_global_load_lds(
      (const __attribute__((address_space(1))) unsigned int*)g,
      (__attribute__((address_space(3))) unsigned int*)l, 16, 0, 0);
}

// ---------------------------------------------------------------------------
// prep: normalize column j (over C), cast bf16, write 32x32x16-fragment-blocked:
//   (j,c) -> uint4 idx ((j>>5)*KC + (c>>4))*64 + ((c>>3)&1)*32 + (j&31)
// (verified layout, rounds 0-12 pass). Single-read: CPT=32 channels held in
// registers; ssq LDS-combined across CSPL c-groups; pack from regs.
// ---------------------------------------------------------------------------
template <int C, int HW, int JPB, int CSPL>
__device__ __forceinline__ void prep_np2(const float* __restrict__ f,
                                         uint4* __restrict__ out, int bid,
                                         float* __restrict__ part) {
  constexpr int CPT = C / CSPL;   // 32 channels per thread (both layers)
  constexpr int BPS = HW / JPB;   // blocks per sample
  const int t = threadIdx.x;
  const int jj = t % JPB;
  const int q = t / JPB;
  const int b = bid / BPS;
  const int j = (bid % BPS) * JPB + jj;
  const float* p = f + (size_t)b * C * HW + j;
  const int cbase = q * CPT;

  float vreg[CPT];
  float ssq = 0.f;
#pragma unroll
  for (int c = 0; c < CPT; ++c) {
    vreg[c] = p[(size_t)(cbase + c) * HW];
    ssq = fmaf(vreg[c], vreg[c], ssq);
  }
  part[q * JPB + jj] = ssq;
  __syncthreads();
  float tot = 0.f;
#pragma unroll
  for (int r = 0; r < CSPL; ++r) tot += part[r * JPB + jj];
  float inv = 1.0f / (sqrtf(tot) + EPS);

  constexpr int KC = C >> 4;
  uint4* ob = out + (size_t)b * (HW >> 5) * KC * 64 + (size_t)(j >> 5) * KC * 64 + (j & 31);
#pragma unroll
  for (int c0 = 0; c0 < CPT; c0 += 8) {
    unsigned w[4];
#pragma unroll
    for (int h = 0; h < 4; ++h)
      w[h] = (unsigned)f2bf(vreg[c0 + 2 * h] * inv) |
             ((unsigned)f2bf(vreg[c0 + 2 * h + 1] * inv) << 16);
    const int cg = cbase + c0;
    ob[(size_t)(cg >> 4) * 64 + ((cg >> 3) & 1) * 32] = make_uint4(w[0], w[1], w[2], w[3]);
  }
}

// prep + init of dE (0xFF), S (0), out (0) in one launch. 1552 blocks.
__global__ __launch_bounds__(256) void prep_all(
    const float* __restrict__ fx1, uint4* __restrict__ fx1B,
    const float* __restrict__ fy1, uint4* __restrict__ fy1B,
    const float* __restrict__ fx2, uint4* __restrict__ fx2B,
    const float* __restrict__ fy2, uint4* __restrict__ fy2B,
    unsigned* __restrict__ dE, float* __restrict__ S, float* __restrict__ out) {
  __shared__ float part[256];
  int bid = blockIdx.x;
  if (bid < 512)        prep_np2<128, 4096, 64, 4>(fx1, fx1B, bid, part);
  else if (bid < 1024)  prep_np2<128, 4096, 64, 4>(fy1, fy1B, bid - 512, part);
  else if (bid < 1280)  prep_np2<256, 1024, 32, 8>(fx2, fx2B, bid - 1024, part);
  else if (bid < 1536)  prep_np2<256, 1024, 32, 8>(fy2, fy2B, bid - 1280, part);
  else {
    int t = (bid - 1536) * 256 + threadIdx.x;  // 16 blocks -> 4096 threads
    for (int k = t; k < 8 * (4096 + 1024); k += 4096) {
      dE[k] = 0xFFFFFFFFu;
      S[k] = 0.f;
    }
    if (t == 0) out[0] = 0.f;
  }
}

// ---------------------------------------------------------------------------
// passA body — round-13: 2-buffer 8 KB double-buffer (16 KB/block), counted
// vmcnt + raw s_barrier (one barrier per phase, same count as the 3-ring).
// Rationale (round-12 arithmetic): structure is LDS-BW-bound (4 waves re-read
// each staged KB: 48 cyc/KB vs 16 cyc MFMA at TI=2), floor ~17 us/pass; the
// 2.6x gap above floor is latency, and residency is the only proven lever
// (occ 31%->43us, 18.8%->48.5us). 16 KB/block + 64 VGPR -> 8 blocks/CU =
// 32 waves/CU (full). Layer1 JSPLIT=16 -> 2048 equal-8-phase blocks, ALL
// co-resident at t=0 (capacity exactly 8/CU) -> L2 sample-locality preserved
// (round-10's thrash was shifted backfill; here L1 has no shift).
// Phase p: barrier (phase p-1 reads done -> buf (p+1)&1 free) -> issue
// stage(p+1) -> vmcnt(2) (= stage p+1's in-flight; oldest-first retire =>
// stage p landed) -> MFMA on buf p&1.
// Register envelope (rounds 2/6/8): bf 64 VGPR + acc 32 AGPR only; bound (256,4).
// ---------------------------------------------------------------------------
template <int HW, int C, int TI, int JSPLIT, int PH>
__device__ __forceinline__ void passA_body(
    const uint4* __restrict__ fxB, const uint4* __restrict__ fyB,
    unsigned* __restrict__ dminEnc, int bid, uint4* __restrict__ smem) {
  constexpr int KC = C / 16;        // chunks per j-tile (8 or 16)
  constexpr int JB = HW / 32;       // 32-wide j-tiles per sample
  constexpr int IBW = 4 * TI;       // 32-wide i-tiles per block
  constexpr int JPS = JB / JSPLIT;  // j-tiles per block
  constexpr int NPH = JPS * PH;     // total phases (8 KB slabs)
  static_assert(KC / PH == 8, "phase slab must be 8 chunks");
  const int lane = threadIdx.x & 63, wv = threadIdx.x >> 6;
  const int sample = bid & 7;       // XCD affinity
  const int rem = bid >> 3;
  const int ib = (rem / JSPLIT) * IBW + wv * TI;
  const int jt0 = (rem % JSPLIT) * JPS;
  const size_t sOff = (size_t)sample * JB * KC * 64;
  const uint4* fx = fxB + sOff;
  const uint4* g0 = fyB + sOff + (size_t)jt0 * KC * 64;  // phases = 512-uint4 slabs

  auto stageP = [&](int p, int bf2) {
#pragma unroll
    for (int r = 0; r < 2; ++r) {
      const int tt = threadIdx.x + r * 256;
      dma16(g0 + (size_t)p * 512 + tt, &smem[bf2 * 512 + tt]);
    }
  };

  stageP(0, 0);  // prologue

  short8 bf[TI][KC];  // persistent fx fragments (B operand, i = cols of D)
#pragma unroll
  for (int ti = 0; ti < TI; ++ti)
#pragma unroll
    for (int kc = 0; kc < KC; ++kc) {
      uint4 t = fx[(size_t)((ib + ti) * KC + kc) * 64 + lane];
      bf[ti][kc] = *(short8*)&t;
    }

  f32x16 z16;  // loop-invariant zero C-operand
#pragma unroll
  for (int r = 0; r < 16; ++r) z16[r] = 0.f;

  float smax[TI];
#pragma unroll
  for (int ti = 0; ti < TI; ++ti) smax[ti] = -1e30f;

  for (int tj = 0; tj < JPS; ++tj) {
    f32x16 acc[TI];
#pragma unroll
    for (int h = 0; h < PH; ++h) {
      const int p = tj * PH + h;
      __builtin_amdgcn_s_barrier();      // prev phase's reads of buf (p+1)&1 done
      if (p + 1 < NPH) {
        stageP(p + 1, (p + 1) & 1);
        asm volatile("s_waitcnt vmcnt(2)" ::: "memory");  // stage p landed
      } else {
        asm volatile("s_waitcnt vmcnt(0)" ::: "memory");
      }
      __builtin_amdgcn_sched_barrier(0);
      __builtin_amdgcn_s_setprio(1);
#pragma unroll
      for (int kc = 0; kc < 8; ++kc) {
        uint4 t = smem[(p & 1) * 512 + kc * 64 + lane];
        short8 a = *(short8*)&t;
#pragma unroll
        for (int ti = 0; ti < TI; ++ti) {
          if (h == 0 && kc == 0)
            acc[ti] = __builtin_amdgcn_mfma_f32_32x32x16_bf16(a, bf[ti][0], z16, 0, 0, 0);
          else
            acc[ti] = __builtin_amdgcn_mfma_f32_32x32x16_bf16(a, bf[ti][h * 8 + kc], acc[ti], 0, 0, 0);
        }
      }
      __builtin_amdgcn_s_setprio(0);
    }
    // max3 tree: depth ~5 instead of 16-deep chain
#pragma unroll
    for (int ti = 0; ti < TI; ++ti) {
      float m0 = fmax3(acc[ti][0], acc[ti][1], acc[ti][2]);
      float m1 = fmax3(acc[ti][3], acc[ti][4], acc[ti][5]);
      float m2 = fmax3(acc[ti][6], acc[ti][7], acc[ti][8]);
      float m3 = fmax3(acc[ti][9], acc[ti][10], acc[ti][11]);
      float m4 = fmax3(acc[ti][12], acc[ti][13], acc[ti][14]);
      float m5 = fmax3(m0, m1, m2);
      float m6 = fmax3(m3, m4, acc[ti][15]);
      smax[ti] = fmax3(smax[ti], m5, m6);
    }
  }

  // rows j live in regs + lane bit5 -> one xor-32 hop; cols i = lane&31
#pragma unroll
  for (int ti = 0; ti < TI; ++ti) {
    float v = smax[ti];
    v = fmaxf(v, __shfl_xor(v, 32));
    if (lane < 32)
      atomicMin(&dminEnc[(size_t)sample * HW + (ib + ti) * 32 + lane],
                encf(1.0f - v));
  }
}

// ---------------------------------------------------------------------------
// passB body: same 2-buffer pipeline; epilogue sum_j exp2(c0 + sim*c1) as a
// pairwise add tree, z16 init-elimination.
// ---------------------------------------------------------------------------
template <int HW, int C, int TI, int JSPLIT, int PH>
__device__ __forceinline__ void passB_body(
    const uint4* __restrict__ fxB, const uint4* __restrict__ fyB,
    const unsigned* __restrict__ dminEnc, float* __restrict__ Ssum,
    int bid, uint4* __restrict__ smem) {
  constexpr int KC = C / 16;
  constexpr int JB = HW / 32;
  constexpr int IBW = 4 * TI;
  constexpr int JPS = JB / JSPLIT;
  constexpr int NPH = JPS * PH;
  static_assert(KC / PH == 8, "phase slab must be 8 chunks");
  const int lane = threadIdx.x & 63, wv = threadIdx.x >> 6;
  const int sample = bid & 7;
  const int rem = bid >> 3;
  const int ib = (rem / JSPLIT) * IBW + wv * TI;
  const int jt0 = (rem % JSPLIT) * JPS;
  const size_t sOff = (size_t)sample * JB * KC * 64;
  const uint4* fx = fxB + sOff;
  const uint4* g0 = fyB + sOff + (size_t)jt0 * KC * 64;

  auto stageP = [&](int p, int bf2) {
#pragma unroll
    for (int r = 0; r < 2; ++r) {
      const int tt = threadIdx.x + r * 256;
      dma16(g0 + (size_t)p * 512 + tt, &smem[bf2 * 512 + tt]);
    }
  };

  stageP(0, 0);

  short8 bf[TI][KC];
#pragma unroll
  for (int ti = 0; ti < TI; ++ti)
#pragma unroll
    for (int kc = 0; kc < KC; ++kc) {
      uint4 t = fx[(size_t)((ib + ti) * KC + kc) * 64 + lane];
      bf[ti][kc] = *(short8*)&t;
    }

  f32x16 z16;
#pragma unroll
  for (int r = 0; r < 16; ++r) z16[r] = 0.f;

  float c0v[TI], c1v[TI];
#pragma unroll
  for (int ti = 0; ti < TI; ++ti) {
    float dmin = decf(dminEnc[(size_t)sample * HW + (ib + ti) * 32 + (lane & 31)]);
    float dinv = 1.0f / (dmin + EPS);
    c1v[ti] = dinv * KEXP;
    c0v[ti] = (1.0f - dinv) * KEXP;
  }

  float ssum[TI];
#pragma unroll
  for (int ti = 0; ti < TI; ++ti) ssum[ti] = 0.f;

  for (int tj = 0; tj < JPS; ++tj) {
    f32x16 acc[TI];
#pragma unroll
    for (int h = 0; h < PH; ++h) {
      const int p = tj * PH + h;
      __builtin_amdgcn_s_barrier();
      if (p + 1 < NPH) {
        stageP(p + 1, (p + 1) & 1);
        asm volatile("s_waitcnt vmcnt(2)" ::: "memory");
      } else {
        asm volatile("s_waitcnt vmcnt(0)" ::: "memory");
      }
      __builtin_amdgcn_sched_barrier(0);
      __builtin_amdgcn_s_setprio(1);
#pragma unroll
      for (int kc = 0; kc < 8; ++kc) {
        uint4 t = smem[(p & 1) * 512 + kc * 64 + lane];
        short8 a = *(short8*)&t;
#pragma unroll
        for (int ti = 0; ti < TI; ++ti) {
          if (h == 0 && kc == 0)
            acc[ti] = __builtin_amdgcn_mfma_f32_32x32x16_bf16(a, bf[ti][0], z16, 0, 0, 0);
          else
            acc[ti] = __builtin_amdgcn_mfma_f32_32x32x16_bf16(a, bf[ti][h * 8 + kc], acc[ti], 0, 0, 0);
        }
      }
      __builtin_amdgcn_s_setprio(0);
    }
    // exp2 + pairwise add tree (chain depth ~5 not 16)
#pragma unroll
    for (int ti = 0; ti < TI; ++ti) {
      float e[16];
#pragma unroll
      for (int r = 0; r < 16; ++r)
        e[r] = __builtin_amdgcn_exp2f(fmaf(acc[ti][r], c1v[ti], c0v[ti]));
#pragma unroll
      for (int r = 0; r < 8; ++r) e[r] += e[r + 8];
#pragma unroll
      for (int r = 0; r < 4; ++r) e[r] += e[r + 4];
      ssum[ti] += (e[0] + e[1]) + (e[2] + e[3]);
    }
  }

#pragma unroll
  for (int ti = 0; ti < TI; ++ti) {
    float v = ssum[ti];
    v += __shfl_xor(v, 32);
    if (lane < 32)
      atomicAdd(&Ssum[(size_t)sample * HW + (ib + ti) * 32 + lane], v);
  }
}

// ---------------------------------------------------------------------------
// Fused launches: layer1 (2048 blocks, JSPLIT=16, PH=1 -> 8 phases) +
// layer2 (512 blocks, JSPLIT=8, PH=2 -> 8 phases; unchanged shape).
// LDS: 2 x 8 KB dbuf = 16 KB -> 8 blocks/CU = 32 waves/CU (full residency).
// All 2048 layer1 blocks co-resident at t=0; layer2 backfills (4 MB buffers).
// __launch_bounds__(256,4): reg cap 128 (never lower — rounds 6/8).
// ---------------------------------------------------------------------------
__global__ __launch_bounds__(256, 4) void passA_all(
    const uint4* __restrict__ fx1B, const uint4* __restrict__ fy1B,
    unsigned* __restrict__ dE1,
    const uint4* __restrict__ fx2B, const uint4* __restrict__ fy2B,
    unsigned* __restrict__ dE2) {
  __shared__ uint4 smem[1024];  // 16 KB: 2-buffer dbuf
  if (blockIdx.x < 2048)
    passA_body<4096, 128, 2, 16, 1>(fx1B, fy1B, dE1, blockIdx.x, smem);
  else
    passA_body<1024, 256, 1, 8, 2>(fx2B, fy2B, dE2, blockIdx.x - 2048, smem);
}

__global__ __launch_bounds__(256, 4) void passB_all(
    const uint4* __restrict__ fx1B, const uint4* __restrict__ fy1B,
    const unsigned* __restrict__ dE1, float* __restrict__ S1,
    const uint4* __restrict__ fx2B, const uint4* __restrict__ fy2B,
    const unsigned* __restrict__ dE2, float* __restrict__ S2) {
  __shared__ uint4 smem[1024];
  if (blockIdx.x < 2048)
    passB_body<4096, 128, 2, 16, 1>(fx1B, fy1B, dE1, S1, blockIdx.x, smem);
  else
    passB_body<1024, 256, 1, 8, 2>(fx2B, fy2B, dE2, S2, blockIdx.x - 2048, smem);
}

// ---------------------------------------------------------------------------
// reduce_out: one block per sample; atomicAdd(-log(cx+EPS)/16) into out[0].
// (Separate tiny kernel; round-11 proved fence-fusing costs 87 us.)
// ---------------------------------------------------------------------------
__global__ __launch_bounds__(256) void reduce_out(
    const unsigned* __restrict__ dE1, const float* __restrict__ S1,
    const unsigned* __restrict__ dE2, const float* __restrict__ S2,
    float* __restrict__ out) {
  const int s = blockIdx.x;
  const unsigned* dE;
  const float* Sp;
  int HW;
  if (s < 8) { dE = dE1 + (size_t)s * 4096; Sp = S1 + (size_t)s * 4096; HW = 4096; }
  else       { dE = dE2 + (size_t)(s - 8) * 1024; Sp = S2 + (size_t)(s - 8) * 1024; HW = 1024; }
  float t = 0.f;
  for (int i = threadIdx.x; i < HW; i += 256) {
    float dmin = decf(dE[i]);
    float dinv = 1.0f / (dmin + EPS);
    float wmx = __builtin_amdgcn_exp2f((1.0f - dmin * dinv) * KEXP);
    t += wmx / (Sp[i] + EPS);
  }
  __shared__ float red[4];
  t += __shfl_xor(t, 1);  t += __shfl_xor(t, 2);  t += __shfl_xor(t, 4);
  t += __shfl_xor(t, 8);  t += __shfl_xor(t, 16); t += __shfl_xor(t, 32);
  if ((threadIdx.x & 63) == 0) red[threadIdx.x >> 6] = t;
  __syncthreads();
  if (threadIdx.x == 0) {
    float cx = (red[0] + red[1] + red[2] + red[3]) / (float)HW;
    atomicAdd(out, -logf(cx + EPS) * (1.0f / 16.0f));
  }
}

extern "C" void kernel_launch(void* const* d_in, const int* in_sizes, int n_in,
                              void* d_out, int out_size, void* d_ws, size_t ws_size,
                              hipStream_t stream) {
  const float* fx1 = (const float*)d_in[0];  // (8,128,64,64)
  const float* fy1 = (const float*)d_in[1];
  const float* fx2 = (const float*)d_in[2];  // (8,256,32,32)
  const float* fy2 = (const float*)d_in[3];
  float* out = (float*)d_out;

  const int B = 8, HW1 = 4096, HW2 = 1024;

  char* w = (char*)d_ws;
  unsigned* dE1 = (unsigned*)w;                      // 8*4096 u32
  unsigned* dE2 = dE1 + (size_t)B * HW1;             // 8*1024 u32
  float*    S1  = (float*)(dE2 + (size_t)B * HW2);   // 8*4096 f
  float*    S2  = S1 + (size_t)B * HW1;              // 8*1024 f
  uint4*    fx1B = (uint4*)((char*)(S2 + (size_t)B * HW2) + 1024);
  const size_t n1 = (size_t)B * (HW1 / 32) * (128 / 16) * 64;  // 8 MB
  const size_t n2 = (size_t)B * (HW2 / 32) * (256 / 16) * 64;  // 4 MB
  uint4* fy1B = fx1B + n1;
  uint4* fx2B = fy1B + n1;
  uint4* fy2B = fx2B + n2;   // total ~24.4 MB

  prep_all<<<1552, 256, 0, stream>>>(fx1, fx1B, fy1, fy1B, fx2, fx2B, fy2, fy2B,
                                     dE1, S1, out);

  passA_all<<<2560, 256, 0, stream>>>(fx1B, fy1B, dE1, fx2B, fy2B, dE2);
  passB_all<<<2560, 256, 0, stream>>>(fx1B, fy1B, dE1, S1, fx2B, fy2B, dE2, S2);

  reduce_out<<<16, 256, 0, stream>>>(dE1, S1, dE2, S2, out);
}

// Round 14
// 167.471 us; speedup vs baseline: 1.7772x; 1.7772x over previous
//
#include <hip/hip_runtime.h>
#include <math.h>

#define EPS 1e-5f
#define KEXP 4.8089834696298780f  // log2(e)/0.3 : exp(x/h) == exp2(x*KEXP)

typedef short short8 __attribute__((ext_vector_type(8)));
typedef float f32x16 __attribute__((ext_vector_type(16)));

static __device__ __forceinline__ unsigned short f2bf(float x) {
  unsigned int b = __float_as_uint(x);
  b += 0x7FFFu + ((b >> 16) & 1u);  // RNE
  return (unsigned short)(b >> 16);
}
static __device__ __forceinline__ unsigned encf(float f) {
  unsigned b = __float_as_uint(f);
  return (b & 0x80000000u) ? ~b : (b | 0x80000000u);
}
static __device__ __forceinline__ float decf(unsigned u) {
  return (u & 0x80000000u) ? __uint_as_float(u & 0x7FFFFFFFu)
                           : __uint_as_float(~u);
}
// nested fmaxf -> clang fuses to v_max3_f32 (T17)
static __device__ __forceinline__ float fmax3(float a, float b, float c) {
  return fmaxf(fmaxf(a, b), c);
}

// async global->LDS, 16B per lane (lane l lands at lds_base + 16*l)
static __device__ __forceinline__ void dma16(const uint4* g, uint4* l) {
  __builtin_amdgcn_global_load_lds(
      (const __attribute__((address_space(1))) unsigned int*)g,
      (__attribute__((address_space(3))) unsigned int*)l, 16, 0, 0);
}

// ---------------------------------------------------------------------------
// prep: normalize column j (over C), cast bf16, write 32x32x16-fragment-blocked:
//   (j,c) -> uint4 idx ((j>>5)*KC + (c>>4))*64 + ((c>>3)&1)*32 + (j&31)
// (verified layout, rounds 0-13 pass). Single-read: CPT=32 channels held in
// registers; ssq LDS-combined across CSPL c-groups; pack from regs.
// ---------------------------------------------------------------------------
template <int C, int HW, int JPB, int CSPL>
__device__ __forceinline__ void prep_np2(const float* __restrict__ f,
                                         uint4* __restrict__ out, int bid,
                                         float* __restrict__ part) {
  constexpr int CPT = C / CSPL;   // 32 channels per thread (both layers)
  constexpr int BPS = HW / JPB;   // blocks per sample
  const int t = threadIdx.x;
  const int jj = t % JPB;
  const int q = t / JPB;
  const int b = bid / BPS;
  const int j = (bid % BPS) * JPB + jj;
  const float* p = f + (size_t)b * C * HW + j;
  const int cbase = q * CPT;

  float vreg[CPT];
  float ssq = 0.f;
#pragma unroll
  for (int c = 0; c < CPT; ++c) {
    vreg[c] = p[(size_t)(cbase + c) * HW];
    ssq = fmaf(vreg[c], vreg[c], ssq);
  }
  part[q * JPB + jj] = ssq;
  __syncthreads();
  float tot = 0.f;
#pragma unroll
  for (int r = 0; r < CSPL; ++r) tot += part[r * JPB + jj];
  float inv = 1.0f / (sqrtf(tot) + EPS);

  constexpr int KC = C >> 4;
  uint4* ob = out + (size_t)b * (HW >> 5) * KC * 64 + (size_t)(j >> 5) * KC * 64 + (j & 31);
#pragma unroll
  for (int c0 = 0; c0 < CPT; c0 += 8) {
    unsigned w[4];
#pragma unroll
    for (int h = 0; h < 4; ++h)
      w[h] = (unsigned)f2bf(vreg[c0 + 2 * h] * inv) |
             ((unsigned)f2bf(vreg[c0 + 2 * h + 1] * inv) << 16);
    const int cg = cbase + c0;
    ob[(size_t)(cg >> 4) * 64 + ((cg >> 3) & 1) * 32] = make_uint4(w[0], w[1], w[2], w[3]);
  }
}

// prep + init of dE (0xFF), S (0), out (0) in one launch. 1552 blocks.
__global__ __launch_bounds__(256) void prep_all(
    const float* __restrict__ fx1, uint4* __restrict__ fx1B,
    const float* __restrict__ fy1, uint4* __restrict__ fy1B,
    const float* __restrict__ fx2, uint4* __restrict__ fx2B,
    const float* __restrict__ fy2, uint4* __restrict__ fy2B,
    unsigned* __restrict__ dE, float* __restrict__ S, float* __restrict__ out) {
  __shared__ float part[256];
  int bid = blockIdx.x;
  if (bid < 512)        prep_np2<128, 4096, 64, 4>(fx1, fx1B, bid, part);
  else if (bid < 1024)  prep_np2<128, 4096, 64, 4>(fy1, fy1B, bid - 512, part);
  else if (bid < 1280)  prep_np2<256, 1024, 32, 8>(fx2, fx2B, bid - 1024, part);
  else if (bid < 1536)  prep_np2<256, 1024, 32, 8>(fy2, fy2B, bid - 1280, part);
  else {
    int t = (bid - 1536) * 256 + threadIdx.x;  // 16 blocks -> 4096 threads
    for (int k = t; k < 8 * (4096 + 1024); k += 4096) {
      dE[k] = 0xFFFFFFFFu;
      S[k] = 0.f;
    }
    if (t == 0) out[0] = 0.f;
  }
}

// ---------------------------------------------------------------------------
// passA body: verified round-7 structure (3 x 8 KB ring, counted vmcnt + raw
// s_barrier, 64 VGPR envelope, z16 init-elimination, max3 tree). Measured
// best: 43.0 us/pass, 167.2/167.8 us total (reproduced twice).
// Walls established by rounds 2-13 (all counter-explained):
//  - reg envelope: bf(64)+acc(32 AGPR) only; occupancy bound must stay 4.
//  - slab size: 16 KB slabs halve residency (48.5 us). Barrier cadence: nil.
//  - grid: MUST be the exact-fit 1536 (JSPLIT=8); JSPLIT=16/grid-2560
//    collapses the memory system (~110 us, ~250 MB phantom traffic, x2).
//  - NO __threadfence in per-block epilogues (130 us).
// This is the plateau of this structural family. DO NOT PERTURB.
// ---------------------------------------------------------------------------
template <int HW, int C, int TI, int JSPLIT, int PH>
__device__ __forceinline__ void passA_body(
    const uint4* __restrict__ fxB, const uint4* __restrict__ fyB,
    unsigned* __restrict__ dminEnc, int bid, uint4* __restrict__ smem) {
  constexpr int KC = C / 16;        // chunks per j-tile (8 or 16)
  constexpr int JB = HW / 32;       // 32-wide j-tiles per sample
  constexpr int IBW = 4 * TI;       // 32-wide i-tiles per block
  constexpr int JPS = JB / JSPLIT;  // j-tiles per block
  constexpr int NPH = JPS * PH;     // total phases (8 KB slabs)
  static_assert(KC / PH == 8, "phase slab must be 8 chunks");
  const int lane = threadIdx.x & 63, wv = threadIdx.x >> 6;
  const int sample = bid & 7;       // XCD affinity
  const int rem = bid >> 3;
  const int ib = (rem / JSPLIT) * IBW + wv * TI;
  const int jt0 = (rem % JSPLIT) * JPS;
  const size_t sOff = (size_t)sample * JB * KC * 64;
  const uint4* fx = fxB + sOff;
  const uint4* g0 = fyB + sOff + (size_t)jt0 * KC * 64;  // phases = 512-uint4 slabs

  auto stageP = [&](int p, int bf3) {
#pragma unroll
    for (int r = 0; r < 2; ++r) {
      const int tt = threadIdx.x + r * 256;
      dma16(g0 + (size_t)p * 512 + tt, &smem[bf3 * 512 + tt]);
    }
  };

  stageP(0, 0);
  stageP(1, 1);

  short8 bf[TI][KC];  // persistent fx fragments (B operand, i = cols of D)
#pragma unroll
  for (int ti = 0; ti < TI; ++ti)
#pragma unroll
    for (int kc = 0; kc < KC; ++kc) {
      uint4 t = fx[(size_t)((ib + ti) * KC + kc) * 64 + lane];
      bf[ti][kc] = *(short8*)&t;
    }

  f32x16 z16;  // loop-invariant zero C-operand
#pragma unroll
  for (int r = 0; r < 16; ++r) z16[r] = 0.f;

  float smax[TI];
#pragma unroll
  for (int ti = 0; ti < TI; ++ti) smax[ti] = -1e30f;

  int bufc = 0, bufs = 2;  // = p%3, (p+2)%3
  for (int tj = 0; tj < JPS; ++tj) {
    f32x16 acc[TI];
#pragma unroll
    for (int h = 0; h < PH; ++h) {
      const int p = tj * PH + h;
      if (p + 1 < NPH) asm volatile("s_waitcnt vmcnt(2)" ::: "memory");
      else             asm volatile("s_waitcnt vmcnt(0)" ::: "memory");
      __builtin_amdgcn_s_barrier();
      __builtin_amdgcn_sched_barrier(0);
      if (p + 2 < NPH) stageP(p + 2, bufs);
      __builtin_amdgcn_s_setprio(1);
#pragma unroll
      for (int kc = 0; kc < 8; ++kc) {
        uint4 t = smem[bufc * 512 + kc * 64 + lane];
        short8 a = *(short8*)&t;
#pragma unroll
        for (int ti = 0; ti < TI; ++ti) {
          if (h == 0 && kc == 0)
            acc[ti] = __builtin_amdgcn_mfma_f32_32x32x16_bf16(a, bf[ti][0], z16, 0, 0, 0);
          else
            acc[ti] = __builtin_amdgcn_mfma_f32_32x32x16_bf16(a, bf[ti][h * 8 + kc], acc[ti], 0, 0, 0);
        }
      }
      __builtin_amdgcn_s_setprio(0);
      bufc = bufc == 2 ? 0 : bufc + 1;
      bufs = bufs == 2 ? 0 : bufs + 1;
    }
    // max3 tree: depth ~5 instead of 16-deep chain
#pragma unroll
    for (int ti = 0; ti < TI; ++ti) {
      float m0 = fmax3(acc[ti][0], acc[ti][1], acc[ti][2]);
      float m1 = fmax3(acc[ti][3], acc[ti][4], acc[ti][5]);
      float m2 = fmax3(acc[ti][6], acc[ti][7], acc[ti][8]);
      float m3 = fmax3(acc[ti][9], acc[ti][10], acc[ti][11]);
      float m4 = fmax3(acc[ti][12], acc[ti][13], acc[ti][14]);
      float m5 = fmax3(m0, m1, m2);
      float m6 = fmax3(m3, m4, acc[ti][15]);
      smax[ti] = fmax3(smax[ti], m5, m6);
    }
  }

  // rows j live in regs + lane bit5 -> one xor-32 hop; cols i = lane&31
#pragma unroll
  for (int ti = 0; ti < TI; ++ti) {
    float v = smax[ti];
    v = fmaxf(v, __shfl_xor(v, 32));
    if (lane < 32)
      atomicMin(&dminEnc[(size_t)sample * HW + (ib + ti) * 32 + lane],
                encf(1.0f - v));
  }
}

// ---------------------------------------------------------------------------
// passB body: same ring pipeline; epilogue sum_j exp2(c0 + sim*c1) as a
// pairwise add tree, z16 init-elimination.
// ---------------------------------------------------------------------------
template <int HW, int C, int TI, int JSPLIT, int PH>
__device__ __forceinline__ void passB_body(
    const uint4* __restrict__ fxB, const uint4* __restrict__ fyB,
    const unsigned* __restrict__ dminEnc, float* __restrict__ Ssum,
    int bid, uint4* __restrict__ smem) {
  constexpr int KC = C / 16;
  constexpr int JB = HW / 32;
  constexpr int IBW = 4 * TI;
  constexpr int JPS = JB / JSPLIT;
  constexpr int NPH = JPS * PH;
  static_assert(KC / PH == 8, "phase slab must be 8 chunks");
  const int lane = threadIdx.x & 63, wv = threadIdx.x >> 6;
  const int sample = bid & 7;
  const int rem = bid >> 3;
  const int ib = (rem / JSPLIT) * IBW + wv * TI;
  const int jt0 = (rem % JSPLIT) * JPS;
  const size_t sOff = (size_t)sample * JB * KC * 64;
  const uint4* fx = fxB + sOff;
  const uint4* g0 = fyB + sOff + (size_t)jt0 * KC * 64;

  auto stageP = [&](int p, int bf3) {
#pragma unroll
    for (int r = 0; r < 2; ++r) {
      const int tt = threadIdx.x + r * 256;
      dma16(g0 + (size_t)p * 512 + tt, &smem[bf3 * 512 + tt]);
    }
  };

  stageP(0, 0);
  stageP(1, 1);

  short8 bf[TI][KC];
#pragma unroll
  for (int ti = 0; ti < TI; ++ti)
#pragma unroll
    for (int kc = 0; kc < KC; ++kc) {
      uint4 t = fx[(size_t)((ib + ti) * KC + kc) * 64 + lane];
      bf[ti][kc] = *(short8*)&t;
    }

  f32x16 z16;
#pragma unroll
  for (int r = 0; r < 16; ++r) z16[r] = 0.f;

  float c0v[TI], c1v[TI];
#pragma unroll
  for (int ti = 0; ti < TI; ++ti) {
    float dmin = decf(dminEnc[(size_t)sample * HW + (ib + ti) * 32 + (lane & 31)]);
    float dinv = 1.0f / (dmin + EPS);
    c1v[ti] = dinv * KEXP;
    c0v[ti] = (1.0f - dinv) * KEXP;
  }

  float ssum[TI];
#pragma unroll
  for (int ti = 0; ti < TI; ++ti) ssum[ti] = 0.f;

  int bufc = 0, bufs = 2;
  for (int tj = 0; tj < JPS; ++tj) {
    f32x16 acc[TI];
#pragma unroll
    for (int h = 0; h < PH; ++h) {
      const int p = tj * PH + h;
      if (p + 1 < NPH) asm volatile("s_waitcnt vmcnt(2)" ::: "memory");
      else             asm volatile("s_waitcnt vmcnt(0)" ::: "memory");
      __builtin_amdgcn_s_barrier();
      __builtin_amdgcn_sched_barrier(0);
      if (p + 2 < NPH) stageP(p + 2, bufs);
      __builtin_amdgcn_s_setprio(1);
#pragma unroll
      for (int kc = 0; kc < 8; ++kc) {
        uint4 t = smem[bufc * 512 + kc * 64 + lane];
        short8 a = *(short8*)&t;
#pragma unroll
        for (int ti = 0; ti < TI; ++ti) {
          if (h == 0 && kc == 0)
            acc[ti] = __builtin_amdgcn_mfma_f32_32x32x16_bf16(a, bf[ti][0], z16, 0, 0, 0);
          else
            acc[ti] = __builtin_amdgcn_mfma_f32_32x32x16_bf16(a, bf[ti][h * 8 + kc], acc[ti], 0, 0, 0);
        }
      }
      __builtin_amdgcn_s_setprio(0);
      bufc = bufc == 2 ? 0 : bufc + 1;
      bufs = bufs == 2 ? 0 : bufs + 1;
    }
    // exp2 + pairwise add tree (chain depth ~5 not 16)
#pragma unroll
    for (int ti = 0; ti < TI; ++ti) {
      float e[16];
#pragma unroll
      for (int r = 0; r < 16; ++r)
        e[r] = __builtin_amdgcn_exp2f(fmaf(acc[ti][r], c1v[ti], c0v[ti]));
#pragma unroll
      for (int r = 0; r < 8; ++r) e[r] += e[r + 8];
#pragma unroll
      for (int r = 0; r < 4; ++r) e[r] += e[r + 4];
      ssum[ti] += (e[0] + e[1]) + (e[2] + e[3]);
    }
  }

#pragma unroll
  for (int ti = 0; ti < TI; ++ti) {
    float v = ssum[ti];
    v += __shfl_xor(v, 32);
    if (lane < 32)
      atomicAdd(&Ssum[(size_t)sample * HW + (ib + ti) * 32 + lane], v);
  }
}

// ---------------------------------------------------------------------------
// Fused launches: layer1 (1024 blocks, PH=1, 16 phases) + layer2 (512 blocks,
// PH=2, 8 phases). LDS: 3 x 8 KB ring = 24 KB. __launch_bounds__(256,4).
// Exact-fit 1536-block grid (6 blocks/CU) — REQUIRED for L2 sample-locality.
// ---------------------------------------------------------------------------
__global__ __launch_bounds__(256, 4) void passA_all(
    const uint4* __restrict__ fx1B, const uint4* __restrict__ fy1B,
    unsigned* __restrict__ dE1,
    const uint4* __restrict__ fx2B, const uint4* __restrict__ fy2B,
    unsigned* __restrict__ dE2) {
  __shared__ uint4 smem[1536];  // 24 KB: 3-buffer ring
  if (blockIdx.x < 1024)
    passA_body<4096, 128, 2, 8, 1>(fx1B, fy1B, dE1, blockIdx.x, smem);
  else
    passA_body<1024, 256, 1, 8, 2>(fx2B, fy2B, dE2, blockIdx.x - 1024, smem);
}

__global__ __launch_bounds__(256, 4) void passB_all(
    const uint4* __restrict__ fx1B, const uint4* __restrict__ fy1B,
    const unsigned* __restrict__ dE1, float* __restrict__ S1,
    const uint4* __restrict__ fx2B, const uint4* __restrict__ fy2B,
    const unsigned* __restrict__ dE2, float* __restrict__ S2) {
  __shared__ uint4 smem[1536];
  if (blockIdx.x < 1024)
    passB_body<4096, 128, 2, 8, 1>(fx1B, fy1B, dE1, S1, blockIdx.x, smem);
  else
    passB_body<1024, 256, 1, 8, 2>(fx2B, fy2B, dE2, S2, blockIdx.x - 1024, smem);
}

// ---------------------------------------------------------------------------
// reduce_out: one block per sample; atomicAdd(-log(cx+EPS)/16) into out[0].
// (Separate tiny kernel; round-11 proved fence-fusing costs 87 us.)
// ---------------------------------------------------------------------------
__global__ __launch_bounds__(256) void reduce_out(
    const unsigned* __restrict__ dE1, const float* __restrict__ S1,
    const unsigned* __restrict__ dE2, const float* __restrict__ S2,
    float* __restrict__ out) {
  const int s = blockIdx.x;
  const unsigned* dE;
  const float* Sp;
  int HW;
  if (s < 8) { dE = dE1 + (size_t)s * 4096; Sp = S1 + (size_t)s * 4096; HW = 4096; }
  else       { dE = dE2 + (size_t)(s - 8) * 1024; Sp = S2 + (size_t)(s - 8) * 1024; HW = 1024; }
  float t = 0.f;
  for (int i = threadIdx.x; i < HW; i += 256) {
    float dmin = decf(dE[i]);
    float dinv = 1.0f / (dmin + EPS);
    float wmx = __builtin_amdgcn_exp2f((1.0f - dmin * dinv) * KEXP);
    t += wmx / (Sp[i] + EPS);
  }
  __shared__ float red[4];
  t += __shfl_xor(t, 1);  t += __shfl_xor(t, 2);  t += __shfl_xor(t, 4);
  t += __shfl_xor(t, 8);  t += __shfl_xor(t, 16); t += __shfl_xor(t, 32);
  if ((threadIdx.x & 63) == 0) red[threadIdx.x >> 6] = t;
  __syncthreads();
  if (threadIdx.x == 0) {
    float cx = (red[0] + red[1] + red[2] + red[3]) / (float)HW;
    atomicAdd(out, -logf(cx + EPS) * (1.0f / 16.0f));
  }
}

extern "C" void kernel_launch(void* const* d_in, const int* in_sizes, int n_in,
                              void* d_out, int out_size, void* d_ws, size_t ws_size,
                              hipStream_t stream) {
  const float* fx1 = (const float*)d_in[0];  // (8,128,64,64)
  const float* fy1 = (const float*)d_in[1];
  const float* fx2 = (const float*)d_in[2];  // (8,256,32,32)
  const float* fy2 = (const float*)d_in[3];
  float* out = (float*)d_out;

  const int B = 8, HW1 = 4096, HW2 = 1024;

  char* w = (char*)d_ws;
  unsigned* dE1 = (unsigned*)w;                      // 8*4096 u32
  unsigned* dE2 = dE1 + (size_t)B * HW1;             // 8*1024 u32
  float*    S1  = (float*)(dE2 + (size_t)B * HW2);   // 8*4096 f
  float*    S2  = S1 + (size_t)B * HW1;              // 8*1024 f
  uint4*    fx1B = (uint4*)((char*)(S2 + (size_t)B * HW2) + 1024);
  const size_t n1 = (size_t)B * (HW1 / 32) * (128 / 16) * 64;  // 8 MB
  const size_t n2 = (size_t)B * (HW2 / 32) * (256 / 16) * 64;  // 4 MB
  uint4* fy1B = fx1B + n1;
  uint4* fx2B = fy1B + n1;
  uint4* fy2B = fx2B + n2;   // total ~24.4 MB

  prep_all<<<1552, 256, 0, stream>>>(fx1, fx1B, fy1, fy1B, fx2, fx2B, fy2, fy2B,
                                     dE1, S1, out);

  passA_all<<<1536, 256, 0, stream>>>(fx1B, fy1B, dE1, fx2B, fy2B, dE2);
  passB_all<<<1536, 256, 0, stream>>>(fx1B, fy1B, dE1, S1, fx2B, fy2B, dE2, S2);

  reduce_out<<<16, 256, 0, stream>>>(dE1, S1, dE2, S2, out);
}

// Round 15
// 165.821 us; speedup vs baseline: 1.7948x; 1.0099x over previous
//
#include <hip/hip_runtime.h>
#include <math.h>

#define EPS 1e-5f
#define KEXP 4.8089834696298780f  // log2(e)/0.3 : exp(x/h) == exp2(x*KEXP)

typedef short short8 __attribute__((ext_vector_type(8)));
typedef float f32x16 __attribute__((ext_vector_type(16)));

static __device__ __forceinline__ unsigned short f2bf(float x) {
  unsigned int b = __float_as_uint(x);
  b += 0x7FFFu + ((b >> 16) & 1u);  // RNE
  return (unsigned short)(b >> 16);
}
static __device__ __forceinline__ unsigned encf(float f) {
  unsigned b = __float_as_uint(f);
  return (b & 0x80000000u) ? ~b : (b | 0x80000000u);
}
static __device__ __forceinline__ float decf(unsigned u) {
  return (u & 0x80000000u) ? __uint_as_float(u & 0x7FFFFFFFu)
                           : __uint_as_float(~u);
}
// nested fmaxf -> clang fuses to v_max3_f32 (T17)
static __device__ __forceinline__ float fmax3(float a, float b, float c) {
  return fmaxf(fmaxf(a, b), c);
}

// async global->LDS, 16B per lane (lane l lands at lds_base + 16*l)
static __device__ __forceinline__ void dma16(const uint4* g, uint4* l) {
  __builtin_amdgcn_global_load_lds(
      (const __attribute__((address_space(1))) unsigned int*)g,
      (__attribute__((address_space(3))) unsigned int*)l, 16, 0, 0);
}

// ---------------------------------------------------------------------------
// prep v4 (round-15): float2 j-vectorization (G13), SAME grid shape as the
// verified v3 (512/512/256/256+16 blocks — the round-1 lesson: never shrink
// a latency-bound kernel's grid). Each thread: 2 adjacent j, CPT=16 channels
// in registers (8 B/lane loads, half the load instrs), ssq LDS-combined
// across CSPL c-groups, pack from regs, two adjacent uint4 stores (coalesced
// in the fragment layout: (j&31) and (j&31)+1 are consecutive uint4s).
// Layout (verified rounds 0-14): (j,c) -> uint4 idx
//   (j>>5)*KC*64 + (c>>4)*64 + ((c>>3)&1)*32 + (j&31),  KC = C/16.
// ---------------------------------------------------------------------------
template <int C, int HW, int JPB, int CSPL>
__device__ __forceinline__ void prep_np3(const float* __restrict__ f,
                                         uint4* __restrict__ out, int bid,
                                         float2* __restrict__ part) {
  constexpr int CPT = C / CSPL;   // 16 channels per thread (both layers)
  constexpr int JPH = JPB / 2;    // j-pairs per block
  constexpr int BPS = HW / JPB;   // blocks per sample
  static_assert(JPH * CSPL == 256, "block must be 256 threads");
  const int t = threadIdx.x;
  const int jj = t % JPH;
  const int q = t / JPH;
  const int b = bid / BPS;
  const int j = (bid % BPS) * JPB + jj * 2;   // even
  const float* p = f + (size_t)b * C * HW + j;
  const int cbase = q * CPT;

  float2 v[CPT];
  float s0 = 0.f, s1 = 0.f;
#pragma unroll
  for (int c = 0; c < CPT; ++c) {
    v[c] = *(const float2*)&p[(size_t)(cbase + c) * HW];
    s0 = fmaf(v[c].x, v[c].x, s0);
    s1 = fmaf(v[c].y, v[c].y, s1);
  }
  part[q * JPH + jj] = make_float2(s0, s1);
  __syncthreads();
  float t0 = 0.f, t1 = 0.f;
#pragma unroll
  for (int r = 0; r < CSPL; ++r) {
    float2 pr = part[r * JPH + jj];
    t0 += pr.x;
    t1 += pr.y;
  }
  float inv0 = 1.0f / (sqrtf(t0) + EPS);
  float inv1 = 1.0f / (sqrtf(t1) + EPS);

  constexpr int KC = C >> 4;
  uint4* ob = out + (size_t)b * (HW >> 5) * KC * 64 + (size_t)(j >> 5) * KC * 64;
  const int jlo = j & 31;  // even, so jlo+1 stays within the 32-group
#pragma unroll
  for (int c0 = 0; c0 < CPT; c0 += 8) {
    const int cg = cbase + c0;
    unsigned w0[4], w1[4];
#pragma unroll
    for (int h = 0; h < 4; ++h) {
      w0[h] = (unsigned)f2bf(v[c0 + 2 * h].x * inv0) |
              ((unsigned)f2bf(v[c0 + 2 * h + 1].x * inv0) << 16);
      w1[h] = (unsigned)f2bf(v[c0 + 2 * h].y * inv1) |
              ((unsigned)f2bf(v[c0 + 2 * h + 1].y * inv1) << 16);
    }
    const size_t koff = (size_t)(cg >> 4) * 64 + ((cg >> 3) & 1) * 32;
    ob[koff + jlo]     = make_uint4(w0[0], w0[1], w0[2], w0[3]);
    ob[koff + jlo + 1] = make_uint4(w1[0], w1[1], w1[2], w1[3]);
  }
}

// prep + init of dE (0xFF), S (0), out (0) in one launch. 1552 blocks.
__global__ __launch_bounds__(256) void prep_all(
    const float* __restrict__ fx1, uint4* __restrict__ fx1B,
    const float* __restrict__ fy1, uint4* __restrict__ fy1B,
    const float* __restrict__ fx2, uint4* __restrict__ fx2B,
    const float* __restrict__ fy2, uint4* __restrict__ fy2B,
    unsigned* __restrict__ dE, float* __restrict__ S, float* __restrict__ out) {
  __shared__ float2 part[256];
  int bid = blockIdx.x;
  if (bid < 512)        prep_np3<128, 4096, 64, 8>(fx1, fx1B, bid, part);
  else if (bid < 1024)  prep_np3<128, 4096, 64, 8>(fy1, fy1B, bid - 512, part);
  else if (bid < 1280)  prep_np3<256, 1024, 32, 16>(fx2, fx2B, bid - 1024, part);
  else if (bid < 1536)  prep_np3<256, 1024, 32, 16>(fy2, fy2B, bid - 1280, part);
  else {
    int t = (bid - 1536) * 256 + threadIdx.x;  // 16 blocks -> 4096 threads
    for (int k = t; k < 8 * (4096 + 1024); k += 4096) {
      dE[k] = 0xFFFFFFFFu;
      S[k] = 0.f;
    }
    if (t == 0) out[0] = 0.f;
  }
}

// ---------------------------------------------------------------------------
// passA body: verified round-7 structure (3 x 8 KB ring, counted vmcnt + raw
// s_barrier, 64 VGPR envelope, z16 init-elimination, max3 tree). Measured
// best: ~42-43 us/pass, 167.2/167.5/167.8 us total (reproduced thrice).
// Walls established by rounds 2-13 (all counter-explained):
//  - reg envelope: bf(64)+acc(32 AGPR) only; occupancy bound must stay 4.
//  - slab size: 16 KB slabs halve residency (48.5 us). Barrier cadence: nil.
//  - grid: MUST be the exact-fit 1536 (JSPLIT=8); JSPLIT=16/grid-2560
//    collapses the memory system (~110 us, ~250 MB phantom traffic, x2).
//  - NO __threadfence in per-block epilogues (130 us).
// This is the plateau of this structural family. DO NOT PERTURB.
// ---------------------------------------------------------------------------
template <int HW, int C, int TI, int JSPLIT, int PH>
__device__ __forceinline__ void passA_body(
    const uint4* __restrict__ fxB, const uint4* __restrict__ fyB,
    unsigned* __restrict__ dminEnc, int bid, uint4* __restrict__ smem) {
  constexpr int KC = C / 16;        // chunks per j-tile (8 or 16)
  constexpr int JB = HW / 32;       // 32-wide j-tiles per sample
  constexpr int IBW = 4 * TI;       // 32-wide i-tiles per block
  constexpr int JPS = JB / JSPLIT;  // j-tiles per block
  constexpr int NPH = JPS * PH;     // total phases (8 KB slabs)
  static_assert(KC / PH == 8, "phase slab must be 8 chunks");
  const int lane = threadIdx.x & 63, wv = threadIdx.x >> 6;
  const int sample = bid & 7;       // XCD affinity
  const int rem = bid >> 3;
  const int ib = (rem / JSPLIT) * IBW + wv * TI;
  const int jt0 = (rem % JSPLIT) * JPS;
  const size_t sOff = (size_t)sample * JB * KC * 64;
  const uint4* fx = fxB + sOff;
  const uint4* g0 = fyB + sOff + (size_t)jt0 * KC * 64;  // phases = 512-uint4 slabs

  auto stageP = [&](int p, int bf3) {
#pragma unroll
    for (int r = 0; r < 2; ++r) {
      const int tt = threadIdx.x + r * 256;
      dma16(g0 + (size_t)p * 512 + tt, &smem[bf3 * 512 + tt]);
    }
  };

  stageP(0, 0);
  stageP(1, 1);

  short8 bf[TI][KC];  // persistent fx fragments (B operand, i = cols of D)
#pragma unroll
  for (int ti = 0; ti < TI; ++ti)
#pragma unroll
    for (int kc = 0; kc < KC; ++kc) {
      uint4 t = fx[(size_t)((ib + ti) * KC + kc) * 64 + lane];
      bf[ti][kc] = *(short8*)&t;
    }

  f32x16 z16;  // loop-invariant zero C-operand
#pragma unroll
  for (int r = 0; r < 16; ++r) z16[r] = 0.f;

  float smax[TI];
#pragma unroll
  for (int ti = 0; ti < TI; ++ti) smax[ti] = -1e30f;

  int bufc = 0, bufs = 2;  // = p%3, (p+2)%3
  for (int tj = 0; tj < JPS; ++tj) {
    f32x16 acc[TI];
#pragma unroll
    for (int h = 0; h < PH; ++h) {
      const int p = tj * PH + h;
      if (p + 1 < NPH) asm volatile("s_waitcnt vmcnt(2)" ::: "memory");
      else             asm volatile("s_waitcnt vmcnt(0)" ::: "memory");
      __builtin_amdgcn_s_barrier();
      __builtin_amdgcn_sched_barrier(0);
      if (p + 2 < NPH) stageP(p + 2, bufs);
      __builtin_amdgcn_s_setprio(1);
#pragma unroll
      for (int kc = 0; kc < 8; ++kc) {
        uint4 t = smem[bufc * 512 + kc * 64 + lane];
        short8 a = *(short8*)&t;
#pragma unroll
        for (int ti = 0; ti < TI; ++ti) {
          if (h == 0 && kc == 0)
            acc[ti] = __builtin_amdgcn_mfma_f32_32x32x16_bf16(a, bf[ti][0], z16, 0, 0, 0);
          else
            acc[ti] = __builtin_amdgcn_mfma_f32_32x32x16_bf16(a, bf[ti][h * 8 + kc], acc[ti], 0, 0, 0);
        }
      }
      __builtin_amdgcn_s_setprio(0);
      bufc = bufc == 2 ? 0 : bufc + 1;
      bufs = bufs == 2 ? 0 : bufs + 1;
    }
    // max3 tree: depth ~5 instead of 16-deep chain
#pragma unroll
    for (int ti = 0; ti < TI; ++ti) {
      float m0 = fmax3(acc[ti][0], acc[ti][1], acc[ti][2]);
      float m1 = fmax3(acc[ti][3], acc[ti][4], acc[ti][5]);
      float m2 = fmax3(acc[ti][6], acc[ti][7], acc[ti][8]);
      float m3 = fmax3(acc[ti][9], acc[ti][10], acc[ti][11]);
      float m4 = fmax3(acc[ti][12], acc[ti][13], acc[ti][14]);
      float m5 = fmax3(m0, m1, m2);
      float m6 = fmax3(m3, m4, acc[ti][15]);
      smax[ti] = fmax3(smax[ti], m5, m6);
    }
  }

  // rows j live in regs + lane bit5 -> one xor-32 hop; cols i = lane&31
#pragma unroll
  for (int ti = 0; ti < TI; ++ti) {
    float v = smax[ti];
    v = fmaxf(v, __shfl_xor(v, 32));
    if (lane < 32)
      atomicMin(&dminEnc[(size_t)sample * HW + (ib + ti) * 32 + lane],
                encf(1.0f - v));
  }
}

// ---------------------------------------------------------------------------
// passB body: same ring pipeline; epilogue sum_j exp2(c0 + sim*c1) as a
// pairwise add tree, z16 init-elimination.
// ---------------------------------------------------------------------------
template <int HW, int C, int TI, int JSPLIT, int PH>
__device__ __forceinline__ void passB_body(
    const uint4* __restrict__ fxB, const uint4* __restrict__ fyB,
    const unsigned* __restrict__ dminEnc, float* __restrict__ Ssum,
    int bid, uint4* __restrict__ smem) {
  constexpr int KC = C / 16;
  constexpr int JB = HW / 32;
  constexpr int IBW = 4 * TI;
  constexpr int JPS = JB / JSPLIT;
  constexpr int NPH = JPS * PH;
  static_assert(KC / PH == 8, "phase slab must be 8 chunks");
  const int lane = threadIdx.x & 63, wv = threadIdx.x >> 6;
  const int sample = bid & 7;
  const int rem = bid >> 3;
  const int ib = (rem / JSPLIT) * IBW + wv * TI;
  const int jt0 = (rem % JSPLIT) * JPS;
  const size_t sOff = (size_t)sample * JB * KC * 64;
  const uint4* fx = fxB + sOff;
  const uint4* g0 = fyB + sOff + (size_t)jt0 * KC * 64;

  auto stageP = [&](int p, int bf3) {
#pragma unroll
    for (int r = 0; r < 2; ++r) {
      const int tt = threadIdx.x + r * 256;
      dma16(g0 + (size_t)p * 512 + tt, &smem[bf3 * 512 + tt]);
    }
  };

  stageP(0, 0);
  stageP(1, 1);

  short8 bf[TI][KC];
#pragma unroll
  for (int ti = 0; ti < TI; ++ti)
#pragma unroll
    for (int kc = 0; kc < KC; ++kc) {
      uint4 t = fx[(size_t)((ib + ti) * KC + kc) * 64 + lane];
      bf[ti][kc] = *(short8*)&t;
    }

  f32x16 z16;
#pragma unroll
  for (int r = 0; r < 16; ++r) z16[r] = 0.f;

  float c0v[TI], c1v[TI];
#pragma unroll
  for (int ti = 0; ti < TI; ++ti) {
    float dmin = decf(dminEnc[(size_t)sample * HW + (ib + ti) * 32 + (lane & 31)]);
    float dinv = 1.0f / (dmin + EPS);
    c1v[ti] = dinv * KEXP;
    c0v[ti] = (1.0f - dinv) * KEXP;
  }

  float ssum[TI];
#pragma unroll
  for (int ti = 0; ti < TI; ++ti) ssum[ti] = 0.f;

  int bufc = 0, bufs = 2;
  for (int tj = 0; tj < JPS; ++tj) {
    f32x16 acc[TI];
#pragma unroll
    for (int h = 0; h < PH; ++h) {
      const int p = tj * PH + h;
      if (p + 1 < NPH) asm volatile("s_waitcnt vmcnt(2)" ::: "memory");
      else             asm volatile("s_waitcnt vmcnt(0)" ::: "memory");
      __builtin_amdgcn_s_barrier();
      __builtin_amdgcn_sched_barrier(0);
      if (p + 2 < NPH) stageP(p + 2, bufs);
      __builtin_amdgcn_s_setprio(1);
#pragma unroll
      for (int kc = 0; kc < 8; ++kc) {
        uint4 t = smem[bufc * 512 + kc * 64 + lane];
        short8 a = *(short8*)&t;
#pragma unroll
        for (int ti = 0; ti < TI; ++ti) {
          if (h == 0 && kc == 0)
            acc[ti] = __builtin_amdgcn_mfma_f32_32x32x16_bf16(a, bf[ti][0], z16, 0, 0, 0);
          else
            acc[ti] = __builtin_amdgcn_mfma_f32_32x32x16_bf16(a, bf[ti][h * 8 + kc], acc[ti], 0, 0, 0);
        }
      }
      __builtin_amdgcn_s_setprio(0);
      bufc = bufc == 2 ? 0 : bufc + 1;
      bufs = bufs == 2 ? 0 : bufs + 1;
    }
    // exp2 + pairwise add tree (chain depth ~5 not 16)
#pragma unroll
    for (int ti = 0; ti < TI; ++ti) {
      float e[16];
#pragma unroll
      for (int r = 0; r < 16; ++r)
        e[r] = __builtin_amdgcn_exp2f(fmaf(acc[ti][r], c1v[ti], c0v[ti]));
#pragma unroll
      for (int r = 0; r < 8; ++r) e[r] += e[r + 8];
#pragma unroll
      for (int r = 0; r < 4; ++r) e[r] += e[r + 4];
      ssum[ti] += (e[0] + e[1]) + (e[2] + e[3]);
    }
  }

#pragma unroll
  for (int ti = 0; ti < TI; ++ti) {
    float v = ssum[ti];
    v += __shfl_xor(v, 32);
    if (lane < 32)
      atomicAdd(&Ssum[(size_t)sample * HW + (ib + ti) * 32 + lane], v);
  }
}

// ---------------------------------------------------------------------------
// Fused launches: layer1 (1024 blocks, PH=1, 16 phases) + layer2 (512 blocks,
// PH=2, 8 phases). LDS: 3 x 8 KB ring = 24 KB. __launch_bounds__(256,4).
// Exact-fit 1536-block grid (6 blocks/CU) — REQUIRED for L2 sample-locality.
// ---------------------------------------------------------------------------
__global__ __launch_bounds__(256, 4) void passA_all(
    const uint4* __restrict__ fx1B, const uint4* __restrict__ fy1B,
    unsigned* __restrict__ dE1,
    const uint4* __restrict__ fx2B, const uint4* __restrict__ fy2B,
    unsigned* __restrict__ dE2) {
  __shared__ uint4 smem[1536];  // 24 KB: 3-buffer ring
  if (blockIdx.x < 1024)
    passA_body<4096, 128, 2, 8, 1>(fx1B, fy1B, dE1, blockIdx.x, smem);
  else
    passA_body<1024, 256, 1, 8, 2>(fx2B, fy2B, dE2, blockIdx.x - 1024, smem);
}

__global__ __launch_bounds__(256, 4) void passB_all(
    const uint4* __restrict__ fx1B, const uint4* __restrict__ fy1B,
    const unsigned* __restrict__ dE1, float* __restrict__ S1,
    const uint4* __restrict__ fx2B, const uint4* __restrict__ fy2B,
    const unsigned* __restrict__ dE2, float* __restrict__ S2) {
  __shared__ uint4 smem[1536];
  if (blockIdx.x < 1024)
    passB_body<4096, 128, 2, 8, 1>(fx1B, fy1B, dE1, S1, blockIdx.x, smem);
  else
    passB_body<1024, 256, 1, 8, 2>(fx2B, fy2B, dE2, S2, blockIdx.x - 1024, smem);
}

// ---------------------------------------------------------------------------
// reduce_out: one block per sample; atomicAdd(-log(cx+EPS)/16) into out[0].
// (Separate tiny kernel; round-11 proved fence-fusing costs 87 us.)
// ---------------------------------------------------------------------------
__global__ __launch_bounds__(256) void reduce_out(
    const unsigned* __restrict__ dE1, const float* __restrict__ S1,
    const unsigned* __restrict__ dE2, const float* __restrict__ S2,
    float* __restrict__ out) {
  const int s = blockIdx.x;
  const unsigned* dE;
  const float* Sp;
  int HW;
  if (s < 8) { dE = dE1 + (size_t)s * 4096; Sp = S1 + (size_t)s * 4096; HW = 4096; }
  else       { dE = dE2 + (size_t)(s - 8) * 1024; Sp = S2 + (size_t)(s - 8) * 1024; HW = 1024; }
  float t = 0.f;
  for (int i = threadIdx.x; i < HW; i += 256) {
    float dmin = decf(dE[i]);
    float dinv = 1.0f / (dmin + EPS);
    float wmx = __builtin_amdgcn_exp2f((1.0f - dmin * dinv) * KEXP);
    t += wmx / (Sp[i] + EPS);
  }
  __shared__ float red[4];
  t += __shfl_xor(t, 1);  t += __shfl_xor(t, 2);  t += __shfl_xor(t, 4);
  t += __shfl_xor(t, 8);  t += __shfl_xor(t, 16); t += __shfl_xor(t, 32);
  if ((threadIdx.x & 63) == 0) red[threadIdx.x >> 6] = t;
  __syncthreads();
  if (threadIdx.x == 0) {
    float cx = (red[0] + red[1] + red[2] + red[3]) / (float)HW;
    atomicAdd(out, -logf(cx + EPS) * (1.0f / 16.0f));
  }
}

extern "C" void kernel_launch(void* const* d_in, const int* in_sizes, int n_in,
                              void* d_out, int out_size, void* d_ws, size_t ws_size,
                              hipStream_t stream) {
  const float* fx1 = (const float*)d_in[0];  // (8,128,64,64)
  const float* fy1 = (const float*)d_in[1];
  const float* fx2 = (const float*)d_in[2];  // (8,256,32,32)
  const float* fy2 = (const float*)d_in[3];
  float* out = (float*)d_out;

  const int B = 8, HW1 = 4096, HW2 = 1024;

  char* w = (char*)d_ws;
  unsigned* dE1 = (unsigned*)w;                      // 8*4096 u32
  unsigned* dE2 = dE1 + (size_t)B * HW1;             // 8*1024 u32
  float*    S1  = (float*)(dE2 + (size_t)B * HW2);   // 8*4096 f
  float*    S2  = S1 + (size_t)B * HW1;              // 8*1024 f
  uint4*    fx1B = (uint4*)((char*)(S2 + (size_t)B * HW2) + 1024);
  const size_t n1 = (size_t)B * (HW1 / 32) * (128 / 16) * 64;  // 8 MB
  const size_t n2 = (size_t)B * (HW2 / 32) * (256 / 16) * 64;  // 4 MB
  uint4* fy1B = fx1B + n1;
  uint4* fx2B = fy1B + n1;
  uint4* fy2B = fx2B + n2;   // total ~24.4 MB

  prep_all<<<1552, 256, 0, stream>>>(fx1, fx1B, fy1, fy1B, fx2, fx2B, fy2, fy2B,
                                     dE1, S1, out);

  passA_all<<<1536, 256, 0, stream>>>(fx1B, fy1B, dE1, fx2B, fy2B, dE2);
  passB_all<<<1536, 256, 0, stream>>>(fx1B, fy1B, dE1, S1, fx2B, fy2B, dE2, S2);

  reduce_out<<<16, 256, 0, stream>>>(dE1, S1, dE2, S2, out);
}